// Round 10
// baseline (509.344 us; speedup 1.0000x reference)
//
#include <hip/hip_runtime.h>
#include <math.h>

#define NNODES 20000
#define NROWP  20096   // padded to multiple of 128
#define NEDGES 320000
#define HDIM   256
#define ODIM   128
#define TSTEPS 3
#define KCAT   512     // [msg | h] concatenated K

typedef __bf16 bf16x8 __attribute__((ext_vector_type(8)));
typedef __bf16 bf16x4 __attribute__((ext_vector_type(4)));
typedef float  f32x4  __attribute__((ext_vector_type(4)));

#define LOG2E 1.44269504f
__device__ __forceinline__ float fexp2_(float x){ return __builtin_amdgcn_exp2f(x); }
__device__ __forceinline__ float frcp_(float x){ return __builtin_amdgcn_rcpf(x); }
__device__ __forceinline__ float fsig_(float x){ return frcp_(1.f + fexp2_(-LOG2E*x)); }
__device__ __forceinline__ float ftanh_(float x){ float t = fexp2_(2.f*LOG2E*x); return 1.f - 2.f*frcp_(t+1.f); }
__device__ __forceinline__ float felu_(float x){ return (x>0.f)? x : (fexp2_(LOG2E*x)-1.f); }

// async global->LDS 16B: per-lane global addr, wave-uniform LDS base (+lane*16 implicit)
__device__ __forceinline__ void load_lds16(const void* g, void* l){
  __builtin_amdgcn_global_load_lds((const __attribute__((address_space(1))) void*)g,
                                   (__attribute__((address_space(3))) void*)l, 16, 0, 0);
}

// BK=64 swizzle (8 granules/row): slot = row*8 + (g ^ (row&7))  [R5/R7: 0 conflicts measured]
__device__ __forceinline__ bf16x8 lds_frag64(const __bf16* Ls, int rowbase, int lane, int kk){
  int row = rowbase + (lane&15);
  int g = (lane>>4) + (kk<<2);
  int slot = (row<<3) + (g ^ (row&7));
  return *(const bf16x8*)&Ls[slot<<3];
}

// ---------------- fused setup: hist || cvt_h || prep_w || zero as_/ad_ ----------------
__global__ void setup1_kernel(const int* __restrict__ dst, int* __restrict__ deg,
                              const float* __restrict__ xc, __bf16* __restrict__ Acat,
                              const float* __restrict__ Wih, const float* __restrict__ Whh,
                              const float* __restrict__ Wg, const float* __restrict__ Lw,
                              __bf16* __restrict__ Bf, __bf16* __restrict__ wgb,
                              __bf16* __restrict__ lwb, float* __restrict__ asad){
  int i = blockIdx.x*blockDim.x + threadIdx.x;   // grid covers NNODES*64 = 1.28M
  if (i < NEDGES) atomicAdd(&deg[dst[i]], 1);
  if (i < NNODES*64){
    int row = i>>6, c = (i&63)<<2;
    float4 v = *(const float4*)&xc[(size_t)row*HDIM + c];
    bf16x4 o; o[0]=(__bf16)v.x; o[1]=(__bf16)v.y; o[2]=(__bf16)v.z; o[3]=(__bf16)v.w;
    *(bf16x4*)&Acat[(size_t)row*KCAT + 256 + c] = o;
  }
  if (i < 1024*128){
    int row = i>>7, kc = (i&127)<<2;
    int gate = row>>8, c = row&255;
    float4 v = make_float4(0,0,0,0);
    if (gate==0 || gate==1){
      v = (kc<256) ? *(const float4*)&Wih[(size_t)(gate*256+c)*HDIM + kc]
                   : *(const float4*)&Whh[(size_t)(gate*256+c)*HDIM + kc-256];
    } else if (gate==2){
      if (kc<256) v = *(const float4*)&Wih[(size_t)(512+c)*HDIM + kc];
    } else {
      if (kc>=256) v = *(const float4*)&Whh[(size_t)(512+c)*HDIM + kc-256];
    }
    bf16x4 o; o[0]=(__bf16)v.x; o[1]=(__bf16)v.y; o[2]=(__bf16)v.z; o[3]=(__bf16)v.w;
    *(bf16x4*)&Bf[(size_t)row*KCAT + kc] = o;
  } else if (i < 1024*128 + 256*64){
    int j = i - 1024*128;
    float4 v = ((const float4*)Wg)[j];
    bf16x4 o; o[0]=(__bf16)v.x; o[1]=(__bf16)v.y; o[2]=(__bf16)v.z; o[3]=(__bf16)v.w;
    ((bf16x4*)wgb)[j] = o;
  } else if (i < 1024*128 + 256*64 + 128*64){
    int j = i - 1024*128 - 256*64;
    float4 v = ((const float4*)Lw)[j];
    bf16x4 o; o[0]=(__bf16)v.x; o[1]=(__bf16)v.y; o[2]=(__bf16)v.z; o[3]=(__bf16)v.w;
    ((bf16x4*)lwb)[j] = o;
  }
  if (i < 2*NNODES) asad[i] = 0.f;
}

// ---------------- fast exclusive scan: 1024 thr x 20 nodes, shfl-scan ----------------
__global__ void scan_kernel(const int* __restrict__ deg, int* __restrict__ rowptr){
  const int PER = 20;
  int tid = threadIdx.x, lane = tid&63, w = tid>>6;
  int base = tid*PER;
  int v[PER]; int s = 0;
  #pragma unroll
  for (int k=0;k<PER;k++){
    v[k] = (base+k < NNODES)? deg[base+k] : 0;
    s += v[k];
  }
  int incl = s;
  #pragma unroll
  for (int off=1; off<64; off<<=1){
    int t = __shfl_up(incl, off);
    if (lane >= off) incl += t;
  }
  __shared__ int wtot[16];
  if (lane==63) wtot[w] = incl;
  __syncthreads();
  if (w==0 && lane<16){
    int x = wtot[lane];
    #pragma unroll
    for (int off=1; off<16; off<<=1){
      int t = __shfl_up(x, off);
      if (lane >= off) x += t;
    }
    wtot[lane] = x;
  }
  __syncthreads();
  int wbase = (w>0)? wtot[w-1] : 0;
  int run = wbase + incl - s;   // exclusive prefix for this thread's range
  #pragma unroll
  for (int k=0;k<PER;k++){
    if (base+k < NNODES) rowptr[base+k] = run;
    run += v[k];
  }
  if (tid==1023) rowptr[NNODES] = wbase + incl;
}

__global__ void scatter_kernel(const int* __restrict__ src, const int* __restrict__ dst,
                               const int* __restrict__ rowptr, int* __restrict__ fill,
                               int* __restrict__ ssrc){
  int e = blockIdx.x*blockDim.x + threadIdx.x;
  if (e < NEDGES){
    int d = dst[e];
    int pos = rowptr[d] + atomicAdd(&fill[d], 1);
    ssrc[pos] = src[e];
  }
}

// ---------------- small-tile BK=64 MFMA GEMM: C[M,Nc] = A[M,256] @ B[Nc,256]^T ----------------
// block: 64 rows x 128 cols, 4 waves (wave 32x64), LDS 24KB -> high occupancy.
// ALPHA: fused att_src/att_dst row-dots via atomics.
template<int YC, bool F32OUT, bool ALPHA>
__global__ __launch_bounds__(256,4)
void mfma_gemm_sm(const __bf16* __restrict__ A, int lda,
                  const __bf16* __restrict__ B,
                  const float* __restrict__ bias,
                  __bf16* __restrict__ Cb, float* __restrict__ Cf,
                  int ldc, int Mreal,
                  const float* __restrict__ att_s, const float* __restrict__ att_d,
                  float* __restrict__ as_, float* __restrict__ ad_){
  __shared__ __bf16 As[64*64];    // 8KB
  __shared__ __bf16 Bs[128*64];   // 16KB
  int bid = blockIdx.x;
  int r0 = (bid/YC)*64, c0 = (bid%YC)*128;
  int tx = threadIdx.x, lane = tx&63, w = tx>>6;
  int rbase = (w&1)*32, cbase = (w>>1)*64;
  f32x4 acc[2][4] = {};
  for (int k0=0; k0<HDIM; k0+=64){
    #pragma unroll
    for (int q=0;q<2;q++){                 // A: 512 granules
      int idx = q*256 + w*64 + lane;
      int row = idx>>3, kg = (idx&7) ^ (row&7);
      load_lds16(A + (size_t)(r0+row)*lda + k0 + (kg<<3),
                 (char*)As + (q*256 + w*64)*16);
    }
    #pragma unroll
    for (int q=0;q<4;q++){                 // B: 1024 granules
      int idx = q*256 + w*64 + lane;
      int row = idx>>3, kg = (idx&7) ^ (row&7);
      load_lds16(B + (size_t)(c0+row)*HDIM + k0 + (kg<<3),
                 (char*)Bs + (q*256 + w*64)*16);
    }
    __syncthreads();
    #pragma unroll
    for (int kk=0;kk<2;kk++){
      bf16x8 a[2], bb[4];
      #pragma unroll
      for (int i=0;i<2;i++) a[i] = lds_frag64(As, rbase + i*16, lane, kk);
      #pragma unroll
      for (int j=0;j<4;j++) bb[j] = lds_frag64(Bs, cbase + j*16, lane, kk);
      #pragma unroll
      for (int i=0;i<2;i++)
        #pragma unroll
        for (int j=0;j<4;j++)
          acc[i][j] = __builtin_amdgcn_mfma_f32_16x16x32_bf16(a[i], bb[j], acc[i][j], 0,0,0);
    }
    __syncthreads();
  }
  int grb = r0 + rbase, gcb = c0 + cbase;
  #pragma unroll
  for (int i=0;i<2;i++){
    #pragma unroll
    for (int j=0;j<4;j++){
      int gc = gcb + j*16 + (lane&15);
      float bv = F32OUT ? bias[gc] : 0.f;
      #pragma unroll
      for (int r=0;r<4;r++){
        int gr = grb + i*16 + ((lane>>4)<<2) + r;
        if (gr >= Mreal) continue;
        float v = acc[i][j][r] + bv;
        if (F32OUT) Cf[(size_t)gr*ldc + gc] = v;
        else        Cb[(size_t)gr*ldc + gc] = (__bf16)v;
      }
    }
  }
  if (ALPHA){
    float ps[2][4] = {}, pd[2][4] = {};
    #pragma unroll
    for (int j=0;j<4;j++){
      int gc = gcb + j*16 + (lane&15);
      float sv = att_s[gc], dv = att_d[gc];
      #pragma unroll
      for (int i=0;i<2;i++)
        #pragma unroll
        for (int r=0;r<4;r++){
          ps[i][r] += acc[i][j][r]*sv;
          pd[i][r] += acc[i][j][r]*dv;
        }
    }
    #pragma unroll
    for (int m=1;m<16;m<<=1){
      #pragma unroll
      for (int i=0;i<2;i++)
        #pragma unroll
        for (int r=0;r<4;r++){
          ps[i][r] += __shfl_xor(ps[i][r], m);
          pd[i][r] += __shfl_xor(pd[i][r], m);
        }
    }
    if ((lane&15)==0){
      #pragma unroll
      for (int i=0;i<2;i++)
        #pragma unroll
        for (int r=0;r<4;r++){
          int gr = grb + i*16 + ((lane>>4)<<2) + r;
          if (gr < Mreal){
            atomicAdd(&as_[gr], ps[i][r]);
            atomicAdd(&ad_[gr], pd[i][r]);
          }
        }
    }
  }
}

// ---------------- GAT softmax+aggregate, XCD-sliced columns ----------------
// grid = 20000 blocks: g=bid>>3 (node octet), xcd=bid&7, slice=xcd>>1 (64 cols), sub=xcd&1.
// Each XCD (bid%8 heuristic) touches only xp cols [slice*64,slice*64+64) = 2.5MB -> L2-resident.
// Wave handles one (node, slice): lane = edge-group(8) x col-chunk(8); 8 edges in flight.
__global__ __launch_bounds__(256,8)
void gat_aggregate_kernel(const __bf16* __restrict__ xpb, const float* __restrict__ as_,
                          const float* __restrict__ ad_, const int* __restrict__ rowptr,
                          const int* __restrict__ ssrc, const float* __restrict__ gat_bias,
                          __bf16* __restrict__ Acat){
  int bid = blockIdx.x;
  int g = bid>>3, xcd = bid&7;
  int slice = xcd>>1, sub = xcd&1;
  int w = threadIdx.x>>6, lane = threadIdx.x&63;
  int node = g*8 + sub*4 + w;          // < 20000 exactly
  int beg = rowptr[node], end = rowptr[node+1];
  int deg = end - beg;
  float adv = ad_[node];
  int eg = lane>>3, cc = lane&7;       // edge-group, col-chunk
  const __bf16* xps = xpb + slice*64;  // column slice base

  float acc[8] = {0,0,0,0,0,0,0,0};

  if (deg <= 64){
    // logits once per wave: lane-per-edge
    float a = -INFINITY; int sreg = 0;
    if (lane < deg){
      sreg = ssrc[beg+lane];
      a = as_[sreg] + adv;
      a = (a>0.f)? a : 0.01f*a;
    }
    float mx = a;
    #pragma unroll
    for (int off=32; off; off>>=1) mx = fmaxf(mx, __shfl_xor(mx,off));
    float e = (lane<deg)? fexp2_(LOG2E*(a-mx)) : 0.f;
    float sm = e;
    #pragma unroll
    for (int off=32; off; off>>=1) sm += __shfl_xor(sm,off);
    float creg = e*frcp_(fmaxf(sm,1e-16f));   // 0 for lanes >= deg

    int rounds = (deg+7)>>3;
    int r = 0;
    for (; r+2<=rounds; r+=2){           // 2 gathers in flight, no divergence (coef=0 pads)
      int e0 = r*8+eg, e1 = e0+8;
      float c0 = __shfl(creg, e0), c1 = __shfl(creg, e1);
      int   r0 = __shfl(sreg, e0), r1 = __shfl(sreg, e1);
      bf16x8 v0 = *(const bf16x8*)&xps[(size_t)r0*HDIM + cc*8];
      bf16x8 v1 = *(const bf16x8*)&xps[(size_t)r1*HDIM + cc*8];
      #pragma unroll
      for (int t=0;t<8;t++) acc[t] += c0*(float)v0[t] + c1*(float)v1[t];
    }
    for (; r<rounds; r++){
      int e0 = r*8+eg;
      float c0 = __shfl(creg, e0);
      int   r0 = __shfl(sreg, e0);
      bf16x8 v0 = *(const bf16x8*)&xps[(size_t)r0*HDIM + cc*8];
      #pragma unroll
      for (int t=0;t<8;t++) acc[t] += c0*(float)v0[t];
    }
  } else {
    // general path (rare): strided logit passes, then per-edge coef recompute
    float mx = -INFINITY;
    for (int e=beg+lane; e<end; e+=64){
      float a = as_[ssrc[e]] + adv;
      a = (a>0.f)? a : 0.01f*a;
      mx = fmaxf(mx, a);
    }
    #pragma unroll
    for (int off=32; off; off>>=1) mx = fmaxf(mx, __shfl_xor(mx,off));
    float sm = 0.f;
    for (int e=beg+lane; e<end; e+=64){
      float a = as_[ssrc[e]] + adv;
      a = (a>0.f)? a : 0.01f*a;
      sm += fexp2_(LOG2E*(a-mx));
    }
    #pragma unroll
    for (int off=32; off; off>>=1) sm += __shfl_xor(sm,off);
    float rsc = frcp_(fmaxf(sm,1e-16f));
    for (int e0=beg; e0<end; e0+=8){
      int e = e0 + eg;
      if (e < end){
        int rw = ssrc[e];
        float a = as_[rw] + adv;
        a = (a>0.f)? a : 0.01f*a;
        float cf = fexp2_(LOG2E*(a-mx))*rsc;
        bf16x8 v = *(const bf16x8*)&xps[(size_t)rw*HDIM + cc*8];
        #pragma unroll
        for (int t=0;t<8;t++) acc[t] += cf*(float)v[t];
      }
    }
  }

  // reduce across the 8 edge-groups (lanes with same cc differ in bits 3..5)
  #pragma unroll
  for (int off=8; off<64; off<<=1)
    #pragma unroll
    for (int t=0;t<8;t++) acc[t] += __shfl_xor(acc[t], off);

  if (eg==0){
    int cbase = slice*64 + cc*8;
    float4 b0 = *(const float4*)&gat_bias[cbase];
    float4 b1 = *(const float4*)&gat_bias[cbase+4];
    float bb[8] = {b0.x,b0.y,b0.z,b0.w,b1.x,b1.y,b1.z,b1.w};
    bf16x8 ov;
    #pragma unroll
    for (int t=0;t<8;t++) ov[t] = (__bf16)felu_(acc[t]+bb[t]);
    *(bf16x8*)&Acat[(size_t)node*KCAT + cbase] = ov;   // msg slot
  }
}

// ---------------- fused GRU: split-K n-gate, 5 blocks/CU ----------------
// phase 0 (k<256): gates {r,z,nx} from Wih; phase 1 (k>=256): {r,z,nh} from Whh.
// block: 64 rows x 64 cols, 4 waves (wave 32x32), LDS 32KB (x5 = 160KB/CU).
__global__ __launch_bounds__(256,5)
void gru_mfma_kernel(const __bf16* __restrict__ Acat, __bf16* __restrict__ AcatN,
                     const __bf16* __restrict__ Bf,
                     const float* __restrict__ bih, const float* __restrict__ bhh,
                     float* __restrict__ as_, float* __restrict__ ad_){
  __shared__ __bf16 As[64*64];    // 8KB
  __shared__ __bf16 Bs[192*64];   // 24KB (3 gate-groups x 64 rows)
  int bid = blockIdx.x;
  int r0 = (bid>>2)*64, c0 = (bid&3)*64;
  int tx = threadIdx.x, lane = tx&63, w = tx>>6;
  int rbase = (w&1)*32, cbase = (w>>1)*32;
  f32x4 accR[2][2]={}, accZ[2][2]={}, accN1[2][2]={}, accN2[2][2]={};
  #pragma unroll
  for (int phase=0; phase<2; phase++){
    int gate2 = 2 + phase;   // nx (Wih_n) or nh (Whh_n) row block of Bf
    for (int k0 = phase*256; k0 < phase*256+256; k0 += 64){
      #pragma unroll
      for (int q=0;q<2;q++){                 // A: 512 granules
        int idx = q*256 + w*64 + lane;
        int row = idx>>3, kg = (idx&7) ^ (row&7);
        load_lds16(Acat + (size_t)(r0+row)*KCAT + k0 + (kg<<3),
                   (char*)As + (q*256 + w*64)*16);
      }
      #pragma unroll
      for (int q=0;q<6;q++){                 // B: 1536 granules (3 gate-groups x 64 cols)
        int idx = q*256 + w*64 + lane;
        int row = idx>>3, kg = (idx&7) ^ (row&7);
        int grp = row>>6, colr = row&63;
        int gate = (grp==2)? gate2 : grp;
        load_lds16(Bf + (size_t)(gate*256 + c0 + colr)*KCAT + k0 + (kg<<3),
                   (char*)Bs + (q*256 + w*64)*16);
      }
      __syncthreads();
      #pragma unroll
      for (int kk=0;kk<2;kk++){
        bf16x8 a[2], bR[2], bZ[2], bN[2];
        #pragma unroll
        for (int i=0;i<2;i++) a[i] = lds_frag64(As, rbase + i*16, lane, kk);
        #pragma unroll
        for (int j=0;j<2;j++){
          bR[j] = lds_frag64(Bs, 0*64 + cbase + j*16, lane, kk);
          bZ[j] = lds_frag64(Bs, 1*64 + cbase + j*16, lane, kk);
          bN[j] = lds_frag64(Bs, 2*64 + cbase + j*16, lane, kk);
        }
        #pragma unroll
        for (int i=0;i<2;i++)
          #pragma unroll
          for (int j=0;j<2;j++){
            accR[i][j] = __builtin_amdgcn_mfma_f32_16x16x32_bf16(a[i], bR[j], accR[i][j], 0,0,0);
            accZ[i][j] = __builtin_amdgcn_mfma_f32_16x16x32_bf16(a[i], bZ[j], accZ[i][j], 0,0,0);
            if (phase==0)
              accN1[i][j] = __builtin_amdgcn_mfma_f32_16x16x32_bf16(a[i], bN[j], accN1[i][j], 0,0,0);
            else
              accN2[i][j] = __builtin_amdgcn_mfma_f32_16x16x32_bf16(a[i], bN[j], accN2[i][j], 0,0,0);
          }
      }
      __syncthreads();
    }
  }
  int grb = r0 + rbase;
  #pragma unroll
  for (int i=0;i<2;i++){
    #pragma unroll
    for (int j=0;j<2;j++){
      int gc = c0 + cbase + j*16 + (lane&15);
      float br_ = bih[gc]     + bhh[gc];
      float bz_ = bih[256+gc] + bhh[256+gc];
      float bnx = bih[512+gc];
      float bnh = bhh[512+gc];
      #pragma unroll
      for (int r=0;r<4;r++){
        int gr = grb + i*16 + ((lane>>4)<<2) + r;
        if (gr >= NNODES) continue;
        float hold = (float)Acat[(size_t)gr*KCAT + 256 + gc];
        float rr = fsig_(accR[i][j][r] + br_);
        float zz = fsig_(accZ[i][j][r] + bz_);
        float nn = ftanh_(accN1[i][j][r] + bnx + rr*(accN2[i][j][r] + bnh));
        AcatN[(size_t)gr*KCAT + 256 + gc] = (__bf16)((1.f-zz)*nn + zz*hold);
      }
    }
  }
  // zero as_/ad_ for the next timestep's fused-alpha atomics
  if ((bid&3)==0 && (w>>1)==0 && (lane&15)==0){
    #pragma unroll
    for (int i=0;i<2;i++)
      #pragma unroll
      for (int r=0;r<4;r++){
        int gr = grb + i*16 + ((lane>>4)<<2) + r;
        if (gr < NNODES){ as_[gr] = 0.f; ad_[gr] = 0.f; }
      }
  }
}

// ---------------- launch ----------------
extern "C" void kernel_launch(void* const* d_in, const int* in_sizes, int n_in,
                              void* d_out, int out_size, void* d_ws, size_t ws_size,
                              hipStream_t stream) {
  const float* x_clique = (const float*)d_in[0];
  const float* W_gat    = (const float*)d_in[1];
  const float* att_src  = (const float*)d_in[2];
  const float* att_dst  = (const float*)d_in[3];
  const float* gat_bias = (const float*)d_in[4];
  const float* W_ih     = (const float*)d_in[5];
  const float* W_hh     = (const float*)d_in[6];
  const float* b_ih     = (const float*)d_in[7];
  const float* b_hh     = (const float*)d_in[8];
  const float* lin_W    = (const float*)d_in[9];
  const float* lin_b    = (const float*)d_in[10];
  const int*   eidx     = (const int*)d_in[14];
  float* out = (float*)d_out;

  const int* src = eidx;
  const int* dst = eidx + NEDGES;

  const size_t ACAT = (size_t)NROWP*KCAT;
  __bf16* AcA  = (__bf16*)d_ws;
  __bf16* AcB  = AcA + ACAT;
  __bf16* xpb  = AcB + ACAT;                        // [NROWP][256]
  __bf16* Bf   = xpb + (size_t)NROWP*HDIM;          // [1024][512]
  __bf16* wgb  = Bf  + (size_t)1024*KCAT;           // [256][256]
  __bf16* lwb  = wgb + (size_t)HDIM*HDIM;           // [128][256]
  float* as_   = (float*)(lwb + (size_t)ODIM*HDIM);
  float* ad_   = as_ + NNODES;
  int* deg     = (int*)(ad_ + NNODES);
  int* fill    = deg + NNODES;
  int* rowptr  = fill + NNODES;
  int* ssrc    = rowptr + (NNODES+1);

  // setup: 1 memset (deg+fill adjacent) + fused setup kernel + scan + scatter
  hipMemsetAsync(deg, 0, 2*NNODES*sizeof(int), stream);
  setup1_kernel<<<NNODES*64/256, 256, 0, stream>>>(
      dst, deg, x_clique, AcA, W_ih, W_hh, W_gat, lin_W, Bf, wgb, lwb, as_);
  scan_kernel<<<1, 1024, 0, stream>>>(deg, rowptr);
  scatter_kernel<<<(NEDGES+255)/256, 256, 0, stream>>>(src, dst, rowptr, fill, ssrc);

  const int RB64 = NROWP/64;   // 314
  __bf16* Ac = AcA;
  __bf16* An = AcB;
  for (int t=0; t<TSTEPS; t++){
    mfma_gemm_sm<2,false,true><<<RB64*2, 256, 0, stream>>>(
        Ac + 256, KCAT, wgb, nullptr, xpb, nullptr, HDIM, NNODES,
        att_src, att_dst, as_, ad_);
    gat_aggregate_kernel<<<NNODES, 256, 0, stream>>>(xpb, as_, ad_, rowptr, ssrc, gat_bias, Ac);
    gru_mfma_kernel<<<RB64*4, 256, 0, stream>>>(Ac, An, Bf, b_ih, b_hh, as_, ad_);
    __bf16* tmp = Ac; Ac = An; An = tmp;
  }
  mfma_gemm_sm<1,true,false><<<RB64, 256, 0, stream>>>(
      Ac + 256, KCAT, lwb, lin_b, nullptr, out, ODIM, NNODES,
      nullptr, nullptr, nullptr, nullptr);
}

// Round 11
// 370.668 us; speedup vs baseline: 1.3741x; 1.3741x over previous
//
#include <hip/hip_runtime.h>
#include <math.h>

#define NNODES 20000
#define NROWP  20096   // padded to multiple of 128
#define NEDGES 320000
#define HDIM   256
#define ODIM   128
#define TSTEPS 3
#define KCAT   512     // [msg | h] concatenated K

typedef __bf16 bf16x8 __attribute__((ext_vector_type(8)));
typedef __bf16 bf16x4 __attribute__((ext_vector_type(4)));
typedef float  f32x4  __attribute__((ext_vector_type(4)));

#define LOG2E 1.44269504f
__device__ __forceinline__ float fexp2_(float x){ return __builtin_amdgcn_exp2f(x); }
__device__ __forceinline__ float frcp_(float x){ return __builtin_amdgcn_rcpf(x); }
__device__ __forceinline__ float fsig_(float x){ return frcp_(1.f + fexp2_(-LOG2E*x)); }
__device__ __forceinline__ float ftanh_(float x){ float t = fexp2_(2.f*LOG2E*x); return 1.f - 2.f*frcp_(t+1.f); }
__device__ __forceinline__ float felu_(float x){ return (x>0.f)? x : (fexp2_(LOG2E*x)-1.f); }

// async global->LDS 16B: per-lane global addr, wave-uniform LDS base (+lane*16 implicit)
__device__ __forceinline__ void load_lds16(const void* g, void* l){
  __builtin_amdgcn_global_load_lds((const __attribute__((address_space(1))) void*)g,
                                   (__attribute__((address_space(3))) void*)l, 16, 0, 0);
}

// BK=64 swizzle (8 granules/row): slot = row*8 + (g ^ (row&7))  [R5/R7: 0 conflicts measured]
__device__ __forceinline__ bf16x8 lds_frag64(const __bf16* Ls, int rowbase, int lane, int kk){
  int row = rowbase + (lane&15);
  int g = (lane>>4) + (kk<<2);
  int slot = (row<<3) + (g ^ (row&7));
  return *(const bf16x8*)&Ls[slot<<3];
}

// ---------------- fused setup: hist || cvt_h || prep_w || zero as_/ad_ ----------------
__global__ void setup1_kernel(const int* __restrict__ dst, int* __restrict__ deg,
                              const float* __restrict__ xc, __bf16* __restrict__ Acat,
                              const float* __restrict__ Wih, const float* __restrict__ Whh,
                              const float* __restrict__ Wg, const float* __restrict__ Lw,
                              __bf16* __restrict__ Bf, __bf16* __restrict__ wgb,
                              __bf16* __restrict__ lwb, float* __restrict__ asad){
  int i = blockIdx.x*blockDim.x + threadIdx.x;   // grid covers NNODES*64 = 1.28M
  if (i < NEDGES) atomicAdd(&deg[dst[i]], 1);
  if (i < NNODES*64){
    int row = i>>6, c = (i&63)<<2;
    float4 v = *(const float4*)&xc[(size_t)row*HDIM + c];
    bf16x4 o; o[0]=(__bf16)v.x; o[1]=(__bf16)v.y; o[2]=(__bf16)v.z; o[3]=(__bf16)v.w;
    *(bf16x4*)&Acat[(size_t)row*KCAT + 256 + c] = o;
  }
  if (i < 1024*128){
    int row = i>>7, kc = (i&127)<<2;
    int gate = row>>8, c = row&255;
    float4 v = make_float4(0,0,0,0);
    if (gate==0 || gate==1){
      v = (kc<256) ? *(const float4*)&Wih[(size_t)(gate*256+c)*HDIM + kc]
                   : *(const float4*)&Whh[(size_t)(gate*256+c)*HDIM + kc-256];
    } else if (gate==2){
      if (kc<256) v = *(const float4*)&Wih[(size_t)(512+c)*HDIM + kc];
    } else {
      if (kc>=256) v = *(const float4*)&Whh[(size_t)(512+c)*HDIM + kc-256];
    }
    bf16x4 o; o[0]=(__bf16)v.x; o[1]=(__bf16)v.y; o[2]=(__bf16)v.z; o[3]=(__bf16)v.w;
    *(bf16x4*)&Bf[(size_t)row*KCAT + kc] = o;
  } else if (i < 1024*128 + 256*64){
    int j = i - 1024*128;
    float4 v = ((const float4*)Wg)[j];
    bf16x4 o; o[0]=(__bf16)v.x; o[1]=(__bf16)v.y; o[2]=(__bf16)v.z; o[3]=(__bf16)v.w;
    ((bf16x4*)wgb)[j] = o;
  } else if (i < 1024*128 + 256*64 + 128*64){
    int j = i - 1024*128 - 256*64;
    float4 v = ((const float4*)Lw)[j];
    bf16x4 o; o[0]=(__bf16)v.x; o[1]=(__bf16)v.y; o[2]=(__bf16)v.z; o[3]=(__bf16)v.w;
    ((bf16x4*)lwb)[j] = o;
  }
  if (i < 2*NNODES) asad[i] = 0.f;
}

// ---------------- fast exclusive scan: 1024 thr x 20 nodes, shfl-scan ----------------
__global__ void scan_kernel(const int* __restrict__ deg, int* __restrict__ rowptr){
  const int PER = 20;
  int tid = threadIdx.x, lane = tid&63, w = tid>>6;
  int base = tid*PER;
  int v[PER]; int s = 0;
  #pragma unroll
  for (int k=0;k<PER;k++){
    v[k] = (base+k < NNODES)? deg[base+k] : 0;
    s += v[k];
  }
  int incl = s;
  #pragma unroll
  for (int off=1; off<64; off<<=1){
    int t = __shfl_up(incl, off);
    if (lane >= off) incl += t;
  }
  __shared__ int wtot[16];
  if (lane==63) wtot[w] = incl;
  __syncthreads();
  if (w==0 && lane<16){
    int x = wtot[lane];
    #pragma unroll
    for (int off=1; off<16; off<<=1){
      int t = __shfl_up(x, off);
      if (lane >= off) x += t;
    }
    wtot[lane] = x;
  }
  __syncthreads();
  int wbase = (w>0)? wtot[w-1] : 0;
  int run = wbase + incl - s;   // exclusive prefix for this thread's range
  #pragma unroll
  for (int k=0;k<PER;k++){
    if (base+k < NNODES) rowptr[base+k] = run;
    run += v[k];
  }
  if (tid==1023) rowptr[NNODES] = wbase + incl;
}

__global__ void scatter_kernel(const int* __restrict__ src, const int* __restrict__ dst,
                               const int* __restrict__ rowptr, int* __restrict__ fill,
                               int* __restrict__ ssrc){
  int e = blockIdx.x*blockDim.x + threadIdx.x;
  if (e < NEDGES){
    int d = dst[e];
    int pos = rowptr[d] + atomicAdd(&fill[d], 1);
    ssrc[pos] = src[e];
  }
}

// ---------------- small-tile BK=64 MFMA GEMM: C[M,Nc] = A[M,256] @ B[Nc,256]^T ----------------
// block: 64 rows x 128 cols, 4 waves (wave 32x64), LDS 24KB -> high occupancy.
// ALPHA: fused att_src/att_dst row-dots via atomics.
template<int YC, bool F32OUT, bool ALPHA>
__global__ __launch_bounds__(256,4)
void mfma_gemm_sm(const __bf16* __restrict__ A, int lda,
                  const __bf16* __restrict__ B,
                  const float* __restrict__ bias,
                  __bf16* __restrict__ Cb, float* __restrict__ Cf,
                  int ldc, int Mreal,
                  const float* __restrict__ att_s, const float* __restrict__ att_d,
                  float* __restrict__ as_, float* __restrict__ ad_){
  __shared__ __bf16 As[64*64];    // 8KB
  __shared__ __bf16 Bs[128*64];   // 16KB
  int bid = blockIdx.x;
  int r0 = (bid/YC)*64, c0 = (bid%YC)*128;
  int tx = threadIdx.x, lane = tx&63, w = tx>>6;
  int rbase = (w&1)*32, cbase = (w>>1)*64;
  f32x4 acc[2][4] = {};
  for (int k0=0; k0<HDIM; k0+=64){
    #pragma unroll
    for (int q=0;q<2;q++){                 // A: 512 granules
      int idx = q*256 + w*64 + lane;
      int row = idx>>3, kg = (idx&7) ^ (row&7);
      load_lds16(A + (size_t)(r0+row)*lda + k0 + (kg<<3),
                 (char*)As + (q*256 + w*64)*16);
    }
    #pragma unroll
    for (int q=0;q<4;q++){                 // B: 1024 granules
      int idx = q*256 + w*64 + lane;
      int row = idx>>3, kg = (idx&7) ^ (row&7);
      load_lds16(B + (size_t)(c0+row)*HDIM + k0 + (kg<<3),
                 (char*)Bs + (q*256 + w*64)*16);
    }
    __syncthreads();
    #pragma unroll
    for (int kk=0;kk<2;kk++){
      bf16x8 a[2], bb[4];
      #pragma unroll
      for (int i=0;i<2;i++) a[i] = lds_frag64(As, rbase + i*16, lane, kk);
      #pragma unroll
      for (int j=0;j<4;j++) bb[j] = lds_frag64(Bs, cbase + j*16, lane, kk);
      #pragma unroll
      for (int i=0;i<2;i++)
        #pragma unroll
        for (int j=0;j<4;j++)
          acc[i][j] = __builtin_amdgcn_mfma_f32_16x16x32_bf16(a[i], bb[j], acc[i][j], 0,0,0);
    }
    __syncthreads();
  }
  int grb = r0 + rbase, gcb = c0 + cbase;
  #pragma unroll
  for (int i=0;i<2;i++){
    #pragma unroll
    for (int j=0;j<4;j++){
      int gc = gcb + j*16 + (lane&15);
      float bv = F32OUT ? bias[gc] : 0.f;
      #pragma unroll
      for (int r=0;r<4;r++){
        int gr = grb + i*16 + ((lane>>4)<<2) + r;
        if (gr >= Mreal) continue;
        float v = acc[i][j][r] + bv;
        if (F32OUT) Cf[(size_t)gr*ldc + gc] = v;
        else        Cb[(size_t)gr*ldc + gc] = (__bf16)v;
      }
    }
  }
  if (ALPHA){
    float ps[2][4] = {}, pd[2][4] = {};
    #pragma unroll
    for (int j=0;j<4;j++){
      int gc = gcb + j*16 + (lane&15);
      float sv = att_s[gc], dv = att_d[gc];
      #pragma unroll
      for (int i=0;i<2;i++)
        #pragma unroll
        for (int r=0;r<4;r++){
          ps[i][r] += acc[i][j][r]*sv;
          pd[i][r] += acc[i][j][r]*dv;
        }
    }
    #pragma unroll
    for (int m=1;m<16;m<<=1){
      #pragma unroll
      for (int i=0;i<2;i++)
        #pragma unroll
        for (int r=0;r<4;r++){
          ps[i][r] += __shfl_xor(ps[i][r], m);
          pd[i][r] += __shfl_xor(pd[i][r], m);
        }
    }
    if ((lane&15)==0){
      #pragma unroll
      for (int i=0;i<2;i++)
        #pragma unroll
        for (int r=0;r<4;r++){
          int gr = grb + i*16 + ((lane>>4)<<2) + r;
          if (gr < Mreal){
            atomicAdd(&as_[gr], ps[i][r]);
            atomicAdd(&ad_[gr], pd[i][r]);
          }
        }
    }
  }
}

// ---------------- GAT softmax+aggregate: one wave/node, 32 lanes/row, 8 gathers in flight ----------------
// (R8 configuration — best measured)
__global__ __launch_bounds__(256,8)
void gat_aggregate_kernel(const __bf16* __restrict__ xpb, const float* __restrict__ as_,
                          const float* __restrict__ ad_, const int* __restrict__ rowptr,
                          const int* __restrict__ ssrc, const float* __restrict__ gat_bias,
                          __bf16* __restrict__ Acat){
  int node = blockIdx.x*4 + (threadIdx.x>>6);
  int lane = threadIdx.x & 63;
  if (node >= NNODES) return;
  int beg = rowptr[node], end = rowptr[node+1];
  int deg = end - beg;
  float adv = ad_[node];
  int half = lane>>5, col = lane&31;

  float acc[8] = {0,0,0,0,0,0,0,0};

  if (deg <= 64){
    float a = -INFINITY; int sreg = 0;
    if (lane < deg){
      sreg = ssrc[beg+lane];
      a = as_[sreg] + adv;
      a = (a>0.f)? a : 0.01f*a;
    }
    float mx = a;
    #pragma unroll
    for (int off=32; off; off>>=1) mx = fmaxf(mx, __shfl_xor(mx,off));
    float e = (lane<deg)? fexp2_(LOG2E*(a-mx)) : 0.f;
    float sm = e;
    #pragma unroll
    for (int off=32; off; off>>=1) sm += __shfl_xor(sm,off);
    float creg = e*frcp_(fmaxf(sm,1e-16f));

    int j = 0;
    for (; j+16<=deg; j+=16){            // 8 gathers in flight per lane
      float cc[8]; int rr[8]; bf16x8 vv[8];
      #pragma unroll
      for (int k=0;k<8;k++){
        cc[k] = __shfl(creg, j+2*k+half);
        rr[k] = __shfl(sreg, j+2*k+half);
      }
      #pragma unroll
      for (int k=0;k<8;k++) vv[k] = *(const bf16x8*)&xpb[(size_t)rr[k]*HDIM + col*8];
      #pragma unroll
      for (int k=0;k<8;k++)
        #pragma unroll
        for (int t=0;t<8;t++) acc[t] += cc[k]*(float)vv[k][t];
    }
    for (; j+8<=deg; j+=8){              // 4 in flight
      float cc[4]; int rr[4]; bf16x8 vv[4];
      #pragma unroll
      for (int k=0;k<4;k++){
        cc[k] = __shfl(creg, j+2*k+half);
        rr[k] = __shfl(sreg, j+2*k+half);
      }
      #pragma unroll
      for (int k=0;k<4;k++) vv[k] = *(const bf16x8*)&xpb[(size_t)rr[k]*HDIM + col*8];
      #pragma unroll
      for (int k=0;k<4;k++)
        #pragma unroll
        for (int t=0;t<8;t++) acc[t] += cc[k]*(float)vv[k][t];
    }
    for (; j+4<=deg; j+=4){              // 2 in flight
      float c0=__shfl(creg,j+half),  c1=__shfl(creg,j+2+half);
      int   r0=__shfl(sreg,j+half),  r1=__shfl(sreg,j+2+half);
      bf16x8 v0 = *(const bf16x8*)&xpb[(size_t)r0*HDIM + col*8];
      bf16x8 v1 = *(const bf16x8*)&xpb[(size_t)r1*HDIM + col*8];
      #pragma unroll
      for (int t=0;t<8;t++) acc[t] += c0*(float)v0[t] + c1*(float)v1[t];
    }
    for (; j<deg; j+=2){
      int jj = j + half;
      float cf = __shfl(creg, jj);
      int   rw = __shfl(sreg, jj);
      if (jj < deg){
        bf16x8 v = *(const bf16x8*)&xpb[(size_t)rw*HDIM + col*8];
        #pragma unroll
        for (int t=0;t<8;t++) acc[t] += cf*(float)v[t];
      }
    }
  } else {
    float mx = -INFINITY;
    for (int e=beg+lane; e<end; e+=64){
      float a = as_[ssrc[e]] + adv;
      a = (a>0.f)? a : 0.01f*a;
      mx = fmaxf(mx, a);
    }
    #pragma unroll
    for (int off=32; off; off>>=1) mx = fmaxf(mx, __shfl_xor(mx,off));
    float sm = 0.f;
    for (int e=beg+lane; e<end; e+=64){
      float a = as_[ssrc[e]] + adv;
      a = (a>0.f)? a : 0.01f*a;
      sm += fexp2_(LOG2E*(a-mx));
    }
    #pragma unroll
    for (int off=32; off; off>>=1) sm += __shfl_xor(sm,off);
    float rsc = frcp_(fmaxf(sm,1e-16f));
    for (int j=0; j<deg; j+=2){
      int jj = j + half;
      if (jj < deg){
        int rw = ssrc[beg+jj];
        float a = as_[rw] + adv;
        a = (a>0.f)? a : 0.01f*a;
        float cf = fexp2_(LOG2E*(a-mx))*rsc;
        bf16x8 v = *(const bf16x8*)&xpb[(size_t)rw*HDIM + col*8];
        #pragma unroll
        for (int t=0;t<8;t++) acc[t] += cf*(float)v[t];
      }
    }
  }

  #pragma unroll
  for (int t=0;t<8;t++) acc[t] += __shfl_down(acc[t], 32);
  if (half==0){
    float4 b0 = *(const float4*)&gat_bias[col*8];
    float4 b1 = *(const float4*)&gat_bias[col*8+4];
    float bb[8] = {b0.x,b0.y,b0.z,b0.w,b1.x,b1.y,b1.z,b1.w};
    bf16x8 ov;
    #pragma unroll
    for (int t=0;t<8;t++) ov[t] = (__bf16)felu_(acc[t]+bb[t]);
    *(bf16x8*)&Acat[(size_t)node*KCAT + col*8] = ov;   // msg slot
  }
}

// ---------------- fused GRU: split-K n-gate, bounds 4 (NO reg spill — R10's bounds-5 spilled) ----------------
// phase 0 (k<256): gates {r,z,nx} from Wih; phase 1 (k>=256): {r,z,nh} from Whh.
// block: 64 rows x 64 cols, 4 waves (wave 32x32), LDS 32KB.
__global__ __launch_bounds__(256,4)
void gru_mfma_kernel(const __bf16* __restrict__ Acat, __bf16* __restrict__ AcatN,
                     const __bf16* __restrict__ Bf,
                     const float* __restrict__ bih, const float* __restrict__ bhh,
                     float* __restrict__ as_, float* __restrict__ ad_){
  __shared__ __bf16 As[64*64];    // 8KB
  __shared__ __bf16 Bs[192*64];   // 24KB (3 gate-groups x 64 rows)
  int bid = blockIdx.x;
  int r0 = (bid>>2)*64, c0 = (bid&3)*64;
  int tx = threadIdx.x, lane = tx&63, w = tx>>6;
  int rbase = (w&1)*32, cbase = (w>>1)*32;
  f32x4 accR[2][2]={}, accZ[2][2]={}, accN1[2][2]={}, accN2[2][2]={};
  #pragma unroll
  for (int phase=0; phase<2; phase++){
    int gate2 = 2 + phase;   // nx (Wih_n) or nh (Whh_n) row block of Bf
    for (int k0 = phase*256; k0 < phase*256+256; k0 += 64){
      #pragma unroll
      for (int q=0;q<2;q++){                 // A: 512 granules
        int idx = q*256 + w*64 + lane;
        int row = idx>>3, kg = (idx&7) ^ (row&7);
        load_lds16(Acat + (size_t)(r0+row)*KCAT + k0 + (kg<<3),
                   (char*)As + (q*256 + w*64)*16);
      }
      #pragma unroll
      for (int q=0;q<6;q++){                 // B: 1536 granules (3 gate-groups x 64 cols)
        int idx = q*256 + w*64 + lane;
        int row = idx>>3, kg = (idx&7) ^ (row&7);
        int grp = row>>6, colr = row&63;
        int gate = (grp==2)? gate2 : grp;
        load_lds16(Bf + (size_t)(gate*256 + c0 + colr)*KCAT + k0 + (kg<<3),
                   (char*)Bs + (q*256 + w*64)*16);
      }
      __syncthreads();
      #pragma unroll
      for (int kk=0;kk<2;kk++){
        bf16x8 a[2], bR[2], bZ[2], bN[2];
        #pragma unroll
        for (int i=0;i<2;i++) a[i] = lds_frag64(As, rbase + i*16, lane, kk);
        #pragma unroll
        for (int j=0;j<2;j++){
          bR[j] = lds_frag64(Bs, 0*64 + cbase + j*16, lane, kk);
          bZ[j] = lds_frag64(Bs, 1*64 + cbase + j*16, lane, kk);
          bN[j] = lds_frag64(Bs, 2*64 + cbase + j*16, lane, kk);
        }
        #pragma unroll
        for (int i=0;i<2;i++)
          #pragma unroll
          for (int j=0;j<2;j++){
            accR[i][j] = __builtin_amdgcn_mfma_f32_16x16x32_bf16(a[i], bR[j], accR[i][j], 0,0,0);
            accZ[i][j] = __builtin_amdgcn_mfma_f32_16x16x32_bf16(a[i], bZ[j], accZ[i][j], 0,0,0);
            if (phase==0)
              accN1[i][j] = __builtin_amdgcn_mfma_f32_16x16x32_bf16(a[i], bN[j], accN1[i][j], 0,0,0);
            else
              accN2[i][j] = __builtin_amdgcn_mfma_f32_16x16x32_bf16(a[i], bN[j], accN2[i][j], 0,0,0);
          }
      }
      __syncthreads();
    }
  }
  int grb = r0 + rbase;
  #pragma unroll
  for (int i=0;i<2;i++){
    #pragma unroll
    for (int j=0;j<2;j++){
      int gc = c0 + cbase + j*16 + (lane&15);
      float br_ = bih[gc]     + bhh[gc];
      float bz_ = bih[256+gc] + bhh[256+gc];
      float bnx = bih[512+gc];
      float bnh = bhh[512+gc];
      #pragma unroll
      for (int r=0;r<4;r++){
        int gr = grb + i*16 + ((lane>>4)<<2) + r;
        if (gr >= NNODES) continue;
        float hold = (float)Acat[(size_t)gr*KCAT + 256 + gc];
        float rr = fsig_(accR[i][j][r] + br_);
        float zz = fsig_(accZ[i][j][r] + bz_);
        float nn = ftanh_(accN1[i][j][r] + bnx + rr*(accN2[i][j][r] + bnh));
        AcatN[(size_t)gr*KCAT + 256 + gc] = (__bf16)((1.f-zz)*nn + zz*hold);
      }
    }
  }
  // zero as_/ad_ for the next timestep's fused-alpha atomics
  if ((bid&3)==0 && (w>>1)==0 && (lane&15)==0){
    #pragma unroll
    for (int i=0;i<2;i++)
      #pragma unroll
      for (int r=0;r<4;r++){
        int gr = grb + i*16 + ((lane>>4)<<2) + r;
        if (gr < NNODES){ as_[gr] = 0.f; ad_[gr] = 0.f; }
      }
  }
}

// ---------------- launch ----------------
extern "C" void kernel_launch(void* const* d_in, const int* in_sizes, int n_in,
                              void* d_out, int out_size, void* d_ws, size_t ws_size,
                              hipStream_t stream) {
  const float* x_clique = (const float*)d_in[0];
  const float* W_gat    = (const float*)d_in[1];
  const float* att_src  = (const float*)d_in[2];
  const float* att_dst  = (const float*)d_in[3];
  const float* gat_bias = (const float*)d_in[4];
  const float* W_ih     = (const float*)d_in[5];
  const float* W_hh     = (const float*)d_in[6];
  const float* b_ih     = (const float*)d_in[7];
  const float* b_hh     = (const float*)d_in[8];
  const float* lin_W    = (const float*)d_in[9];
  const float* lin_b    = (const float*)d_in[10];
  const int*   eidx     = (const int*)d_in[14];
  float* out = (float*)d_out;

  const int* src = eidx;
  const int* dst = eidx + NEDGES;

  const size_t ACAT = (size_t)NROWP*KCAT;
  __bf16* AcA  = (__bf16*)d_ws;
  __bf16* AcB  = AcA + ACAT;
  __bf16* xpb  = AcB + ACAT;                        // [NROWP][256]
  __bf16* Bf   = xpb + (size_t)NROWP*HDIM;          // [1024][512]
  __bf16* wgb  = Bf  + (size_t)1024*KCAT;           // [256][256]
  __bf16* lwb  = wgb + (size_t)HDIM*HDIM;           // [128][256]
  float* as_   = (float*)(lwb + (size_t)ODIM*HDIM);
  float* ad_   = as_ + NNODES;
  int* deg     = (int*)(ad_ + NNODES);
  int* fill    = deg + NNODES;
  int* rowptr  = fill + NNODES;
  int* ssrc    = rowptr + (NNODES+1);

  // setup: 1 memset (deg+fill adjacent) + fused setup kernel + scan + scatter
  hipMemsetAsync(deg, 0, 2*NNODES*sizeof(int), stream);
  setup1_kernel<<<NNODES*64/256, 256, 0, stream>>>(
      dst, deg, x_clique, AcA, W_ih, W_hh, W_gat, lin_W, Bf, wgb, lwb, as_);
  scan_kernel<<<1, 1024, 0, stream>>>(deg, rowptr);
  scatter_kernel<<<(NEDGES+255)/256, 256, 0, stream>>>(src, dst, rowptr, fill, ssrc);

  const int RB64 = NROWP/64;   // 314
  __bf16* Ac = AcA;
  __bf16* An = AcB;
  for (int t=0; t<TSTEPS; t++){
    mfma_gemm_sm<2,false,true><<<RB64*2, 256, 0, stream>>>(
        Ac + 256, KCAT, wgb, nullptr, xpb, nullptr, HDIM, NNODES,
        att_src, att_dst, as_, ad_);
    gat_aggregate_kernel<<<(NNODES+3)/4, 256, 0, stream>>>(xpb, as_, ad_, rowptr, ssrc, gat_bias, Ac);
    gru_mfma_kernel<<<RB64*4, 256, 0, stream>>>(Ac, An, Bf, b_ih, b_hh, as_, ad_);
    __bf16* tmp = Ac; Ac = An; An = tmp;
  }
  mfma_gemm_sm<1,true,false><<<RB64, 256, 0, stream>>>(
      Ac + 256, KCAT, lwb, lin_b, nullptr, out, ODIM, NNODES,
      nullptr, nullptr, nullptr, nullptr);
}

// Round 12
// 357.027 us; speedup vs baseline: 1.4266x; 1.0382x over previous
//
#include <hip/hip_runtime.h>
#include <math.h>

#define NNODES 20000
#define NROWP  20096   // padded to multiple of 128
#define NEDGES 320000
#define HDIM   256
#define ODIM   128
#define TSTEPS 3
#define KCAT   512     // [msg | h] concatenated K

typedef __bf16 bf16x8 __attribute__((ext_vector_type(8)));
typedef __bf16 bf16x4 __attribute__((ext_vector_type(4)));
typedef float  f32x4  __attribute__((ext_vector_type(4)));

#define LOG2E 1.44269504f
__device__ __forceinline__ float fexp2_(float x){ return __builtin_amdgcn_exp2f(x); }
__device__ __forceinline__ float frcp_(float x){ return __builtin_amdgcn_rcpf(x); }
__device__ __forceinline__ float fsig_(float x){ return frcp_(1.f + fexp2_(-LOG2E*x)); }
__device__ __forceinline__ float ftanh_(float x){ float t = fexp2_(2.f*LOG2E*x); return 1.f - 2.f*frcp_(t+1.f); }
__device__ __forceinline__ float felu_(float x){ return (x>0.f)? x : (fexp2_(LOG2E*x)-1.f); }

// async global->LDS 16B: per-lane global addr, wave-uniform LDS base (+lane*16 implicit)
__device__ __forceinline__ void load_lds16(const void* g, void* l){
  __builtin_amdgcn_global_load_lds((const __attribute__((address_space(1))) void*)g,
                                   (__attribute__((address_space(3))) void*)l, 16, 0, 0);
}

// BK=64 swizzle (8 granules/row): slot = row*8 + (g ^ (row&7))  [R5/R7: 0 conflicts measured]
__device__ __forceinline__ bf16x8 lds_frag64(const __bf16* Ls, int rowbase, int lane, int kk){
  int row = rowbase + (lane&15);
  int g = (lane>>4) + (kk<<2);
  int slot = (row<<3) + (g ^ (row&7));
  return *(const bf16x8*)&Ls[slot<<3];
}

// ---------------- fused setup: hist || cvt_h || prep_w || zero as_/ad_ ----------------
__global__ void setup1_kernel(const int* __restrict__ dst, int* __restrict__ deg,
                              const float* __restrict__ xc, __bf16* __restrict__ Acat,
                              const float* __restrict__ Wih, const float* __restrict__ Whh,
                              const float* __restrict__ Wg, const float* __restrict__ Lw,
                              __bf16* __restrict__ Bf, __bf16* __restrict__ wgb,
                              __bf16* __restrict__ lwb, float* __restrict__ asad){
  int i = blockIdx.x*blockDim.x + threadIdx.x;   // grid covers NNODES*64 = 1.28M
  if (i < NEDGES) atomicAdd(&deg[dst[i]], 1);
  if (i < NNODES*64){
    int row = i>>6, c = (i&63)<<2;
    float4 v = *(const float4*)&xc[(size_t)row*HDIM + c];
    bf16x4 o; o[0]=(__bf16)v.x; o[1]=(__bf16)v.y; o[2]=(__bf16)v.z; o[3]=(__bf16)v.w;
    *(bf16x4*)&Acat[(size_t)row*KCAT + 256 + c] = o;
  }
  if (i < 1024*128){
    int row = i>>7, kc = (i&127)<<2;
    int gate = row>>8, c = row&255;
    float4 v = make_float4(0,0,0,0);
    if (gate==0 || gate==1){
      v = (kc<256) ? *(const float4*)&Wih[(size_t)(gate*256+c)*HDIM + kc]
                   : *(const float4*)&Whh[(size_t)(gate*256+c)*HDIM + kc-256];
    } else if (gate==2){
      if (kc<256) v = *(const float4*)&Wih[(size_t)(512+c)*HDIM + kc];
    } else {
      if (kc>=256) v = *(const float4*)&Whh[(size_t)(512+c)*HDIM + kc-256];
    }
    bf16x4 o; o[0]=(__bf16)v.x; o[1]=(__bf16)v.y; o[2]=(__bf16)v.z; o[3]=(__bf16)v.w;
    *(bf16x4*)&Bf[(size_t)row*KCAT + kc] = o;
  } else if (i < 1024*128 + 256*64){
    int j = i - 1024*128;
    float4 v = ((const float4*)Wg)[j];
    bf16x4 o; o[0]=(__bf16)v.x; o[1]=(__bf16)v.y; o[2]=(__bf16)v.z; o[3]=(__bf16)v.w;
    ((bf16x4*)wgb)[j] = o;
  } else if (i < 1024*128 + 256*64 + 128*64){
    int j = i - 1024*128 - 256*64;
    float4 v = ((const float4*)Lw)[j];
    bf16x4 o; o[0]=(__bf16)v.x; o[1]=(__bf16)v.y; o[2]=(__bf16)v.z; o[3]=(__bf16)v.w;
    ((bf16x4*)lwb)[j] = o;
  }
  if (i < 2*NNODES) asad[i] = 0.f;
}

// ---------------- fast exclusive scan: 1024 thr x 20 nodes, shfl-scan ----------------
__global__ void scan_kernel(const int* __restrict__ deg, int* __restrict__ rowptr){
  const int PER = 20;
  int tid = threadIdx.x, lane = tid&63, w = tid>>6;
  int base = tid*PER;
  int v[PER]; int s = 0;
  #pragma unroll
  for (int k=0;k<PER;k++){
    v[k] = (base+k < NNODES)? deg[base+k] : 0;
    s += v[k];
  }
  int incl = s;
  #pragma unroll
  for (int off=1; off<64; off<<=1){
    int t = __shfl_up(incl, off);
    if (lane >= off) incl += t;
  }
  __shared__ int wtot[16];
  if (lane==63) wtot[w] = incl;
  __syncthreads();
  if (w==0 && lane<16){
    int x = wtot[lane];
    #pragma unroll
    for (int off=1; off<16; off<<=1){
      int t = __shfl_up(x, off);
      if (lane >= off) x += t;
    }
    wtot[lane] = x;
  }
  __syncthreads();
  int wbase = (w>0)? wtot[w-1] : 0;
  int run = wbase + incl - s;   // exclusive prefix for this thread's range
  #pragma unroll
  for (int k=0;k<PER;k++){
    if (base+k < NNODES) rowptr[base+k] = run;
    run += v[k];
  }
  if (tid==1023) rowptr[NNODES] = wbase + incl;
}

__global__ void scatter_kernel(const int* __restrict__ src, const int* __restrict__ dst,
                               const int* __restrict__ rowptr, int* __restrict__ fill,
                               int* __restrict__ ssrc){
  int e = blockIdx.x*blockDim.x + threadIdx.x;
  if (e < NEDGES){
    int d = dst[e];
    int pos = rowptr[d] + atomicAdd(&fill[d], 1);
    ssrc[pos] = src[e];
  }
}

// ---------------- small-tile BK=64 MFMA GEMM: C[M,Nc] = A[M,256] @ B[Nc,256]^T ----------------
// block: 64 rows x 128 cols, 4 waves (wave 32x64), LDS 24KB -> high occupancy.
// ALPHA: fused att_src/att_dst row-dots via atomics.
template<int YC, bool F32OUT, bool ALPHA>
__global__ __launch_bounds__(256,4)
void mfma_gemm_sm(const __bf16* __restrict__ A, int lda,
                  const __bf16* __restrict__ B,
                  const float* __restrict__ bias,
                  __bf16* __restrict__ Cb, float* __restrict__ Cf,
                  int ldc, int Mreal,
                  const float* __restrict__ att_s, const float* __restrict__ att_d,
                  float* __restrict__ as_, float* __restrict__ ad_){
  __shared__ __bf16 As[64*64];    // 8KB
  __shared__ __bf16 Bs[128*64];   // 16KB
  int bid = blockIdx.x;
  int r0 = (bid/YC)*64, c0 = (bid%YC)*128;
  int tx = threadIdx.x, lane = tx&63, w = tx>>6;
  int rbase = (w&1)*32, cbase = (w>>1)*64;
  f32x4 acc[2][4] = {};
  for (int k0=0; k0<HDIM; k0+=64){
    #pragma unroll
    for (int q=0;q<2;q++){                 // A: 512 granules
      int idx = q*256 + w*64 + lane;
      int row = idx>>3, kg = (idx&7) ^ (row&7);
      load_lds16(A + (size_t)(r0+row)*lda + k0 + (kg<<3),
                 (char*)As + (q*256 + w*64)*16);
    }
    #pragma unroll
    for (int q=0;q<4;q++){                 // B: 1024 granules
      int idx = q*256 + w*64 + lane;
      int row = idx>>3, kg = (idx&7) ^ (row&7);
      load_lds16(B + (size_t)(c0+row)*HDIM + k0 + (kg<<3),
                 (char*)Bs + (q*256 + w*64)*16);
    }
    __syncthreads();
    #pragma unroll
    for (int kk=0;kk<2;kk++){
      bf16x8 a[2], bb[4];
      #pragma unroll
      for (int i=0;i<2;i++) a[i] = lds_frag64(As, rbase + i*16, lane, kk);
      #pragma unroll
      for (int j=0;j<4;j++) bb[j] = lds_frag64(Bs, cbase + j*16, lane, kk);
      #pragma unroll
      for (int i=0;i<2;i++)
        #pragma unroll
        for (int j=0;j<4;j++)
          acc[i][j] = __builtin_amdgcn_mfma_f32_16x16x32_bf16(a[i], bb[j], acc[i][j], 0,0,0);
    }
    __syncthreads();
  }
  int grb = r0 + rbase, gcb = c0 + cbase;
  #pragma unroll
  for (int i=0;i<2;i++){
    #pragma unroll
    for (int j=0;j<4;j++){
      int gc = gcb + j*16 + (lane&15);
      float bv = F32OUT ? bias[gc] : 0.f;
      #pragma unroll
      for (int r=0;r<4;r++){
        int gr = grb + i*16 + ((lane>>4)<<2) + r;
        if (gr >= Mreal) continue;
        float v = acc[i][j][r] + bv;
        if (F32OUT) Cf[(size_t)gr*ldc + gc] = v;
        else        Cb[(size_t)gr*ldc + gc] = (__bf16)v;
      }
    }
  }
  if (ALPHA){
    float ps[2][4] = {}, pd[2][4] = {};
    #pragma unroll
    for (int j=0;j<4;j++){
      int gc = gcb + j*16 + (lane&15);
      float sv = att_s[gc], dv = att_d[gc];
      #pragma unroll
      for (int i=0;i<2;i++)
        #pragma unroll
        for (int r=0;r<4;r++){
          ps[i][r] += acc[i][j][r]*sv;
          pd[i][r] += acc[i][j][r]*dv;
        }
    }
    #pragma unroll
    for (int m=1;m<16;m<<=1){
      #pragma unroll
      for (int i=0;i<2;i++)
        #pragma unroll
        for (int r=0;r<4;r++){
          ps[i][r] += __shfl_xor(ps[i][r], m);
          pd[i][r] += __shfl_xor(pd[i][r], m);
        }
    }
    if ((lane&15)==0){
      #pragma unroll
      for (int i=0;i<2;i++)
        #pragma unroll
        for (int r=0;r<4;r++){
          int gr = grb + i*16 + ((lane>>4)<<2) + r;
          if (gr < Mreal){
            atomicAdd(&as_[gr], ps[i][r]);
            atomicAdd(&ad_[gr], pd[i][r]);
          }
        }
    }
  }
}

// ---------------- GAT softmax+aggregate: one wave/node, 32 lanes/row, 8 gathers in flight ----------------
__global__ __launch_bounds__(256,8)
void gat_aggregate_kernel(const __bf16* __restrict__ xpb, const float* __restrict__ as_,
                          const float* __restrict__ ad_, const int* __restrict__ rowptr,
                          const int* __restrict__ ssrc, const float* __restrict__ gat_bias,
                          __bf16* __restrict__ Acat){
  int node = blockIdx.x*4 + (threadIdx.x>>6);
  int lane = threadIdx.x & 63;
  if (node >= NNODES) return;
  int beg = rowptr[node], end = rowptr[node+1];
  int deg = end - beg;
  float adv = ad_[node];
  int half = lane>>5, col = lane&31;

  float acc[8] = {0,0,0,0,0,0,0,0};

  if (deg <= 64){
    float a = -INFINITY; int sreg = 0;
    if (lane < deg){
      sreg = ssrc[beg+lane];
      a = as_[sreg] + adv;
      a = (a>0.f)? a : 0.01f*a;
    }
    float mx = a;
    #pragma unroll
    for (int off=32; off; off>>=1) mx = fmaxf(mx, __shfl_xor(mx,off));
    float e = (lane<deg)? fexp2_(LOG2E*(a-mx)) : 0.f;
    float sm = e;
    #pragma unroll
    for (int off=32; off; off>>=1) sm += __shfl_xor(sm,off);
    float creg = e*frcp_(fmaxf(sm,1e-16f));

    int j = 0;
    for (; j+16<=deg; j+=16){            // 8 gathers in flight per lane
      float cc[8]; int rr[8]; bf16x8 vv[8];
      #pragma unroll
      for (int k=0;k<8;k++){
        cc[k] = __shfl(creg, j+2*k+half);
        rr[k] = __shfl(sreg, j+2*k+half);
      }
      #pragma unroll
      for (int k=0;k<8;k++) vv[k] = *(const bf16x8*)&xpb[(size_t)rr[k]*HDIM + col*8];
      #pragma unroll
      for (int k=0;k<8;k++)
        #pragma unroll
        for (int t=0;t<8;t++) acc[t] += cc[k]*(float)vv[k][t];
    }
    for (; j+8<=deg; j+=8){              // 4 in flight
      float cc[4]; int rr[4]; bf16x8 vv[4];
      #pragma unroll
      for (int k=0;k<4;k++){
        cc[k] = __shfl(creg, j+2*k+half);
        rr[k] = __shfl(sreg, j+2*k+half);
      }
      #pragma unroll
      for (int k=0;k<4;k++) vv[k] = *(const bf16x8*)&xpb[(size_t)rr[k]*HDIM + col*8];
      #pragma unroll
      for (int k=0;k<4;k++)
        #pragma unroll
        for (int t=0;t<8;t++) acc[t] += cc[k]*(float)vv[k][t];
    }
    for (; j+4<=deg; j+=4){              // 2 in flight
      float c0=__shfl(creg,j+half),  c1=__shfl(creg,j+2+half);
      int   r0=__shfl(sreg,j+half),  r1=__shfl(sreg,j+2+half);
      bf16x8 v0 = *(const bf16x8*)&xpb[(size_t)r0*HDIM + col*8];
      bf16x8 v1 = *(const bf16x8*)&xpb[(size_t)r1*HDIM + col*8];
      #pragma unroll
      for (int t=0;t<8;t++) acc[t] += c0*(float)v0[t] + c1*(float)v1[t];
    }
    for (; j<deg; j+=2){
      int jj = j + half;
      float cf = __shfl(creg, jj);
      int   rw = __shfl(sreg, jj);
      if (jj < deg){
        bf16x8 v = *(const bf16x8*)&xpb[(size_t)rw*HDIM + col*8];
        #pragma unroll
        for (int t=0;t<8;t++) acc[t] += cf*(float)v[t];
      }
    }
  } else {
    float mx = -INFINITY;
    for (int e=beg+lane; e<end; e+=64){
      float a = as_[ssrc[e]] + adv;
      a = (a>0.f)? a : 0.01f*a;
      mx = fmaxf(mx, a);
    }
    #pragma unroll
    for (int off=32; off; off>>=1) mx = fmaxf(mx, __shfl_xor(mx,off));
    float sm = 0.f;
    for (int e=beg+lane; e<end; e+=64){
      float a = as_[ssrc[e]] + adv;
      a = (a>0.f)? a : 0.01f*a;
      sm += fexp2_(LOG2E*(a-mx));
    }
    #pragma unroll
    for (int off=32; off; off>>=1) sm += __shfl_xor(sm,off);
    float rsc = frcp_(fmaxf(sm,1e-16f));
    for (int j=0; j<deg; j+=2){
      int jj = j + half;
      if (jj < deg){
        int rw = ssrc[beg+jj];
        float a = as_[rw] + adv;
        a = (a>0.f)? a : 0.01f*a;
        float cf = fexp2_(LOG2E*(a-mx))*rsc;
        bf16x8 v = *(const bf16x8*)&xpb[(size_t)rw*HDIM + col*8];
        #pragma unroll
        for (int t=0;t<8;t++) acc[t] += cf*(float)v[t];
      }
    }
  }

  #pragma unroll
  for (int t=0;t<8;t++) acc[t] += __shfl_down(acc[t], 32);
  if (half==0){
    float4 b0 = *(const float4*)&gat_bias[col*8];
    float4 b1 = *(const float4*)&gat_bias[col*8+4];
    float bb[8] = {b0.x,b0.y,b0.z,b0.w,b1.x,b1.y,b1.z,b1.w};
    bf16x8 ov;
    #pragma unroll
    for (int t=0;t<8;t++) ov[t] = (__bf16)felu_(acc[t]+bb[t]);
    *(bf16x8*)&Acat[(size_t)node*KCAT + col*8] = ov;   // msg slot
  }
}

// ---------------- fused GRU: 4-gate Bf, small tile (R8 config — best measured) ----------------
// block: 64 rows x 64 cols x 4 gates, 4 waves (wave 32x32x4g, acc=64 AGPR), LDS 40KB.
__global__ __launch_bounds__(256,4)
void gru_mfma_kernel(const __bf16* __restrict__ Acat, __bf16* __restrict__ AcatN,
                     const __bf16* __restrict__ Bf,
                     const float* __restrict__ bih, const float* __restrict__ bhh,
                     float* __restrict__ as_, float* __restrict__ ad_){
  __shared__ __bf16 As[64*64];    // 8KB
  __shared__ __bf16 Bs[256*64];   // 32KB
  int bid = blockIdx.x;
  int r0 = (bid>>2)*64, c0 = (bid&3)*64;
  int tx = threadIdx.x, lane = tx&63, w = tx>>6;
  int rbase = (w&1)*32, cbase = (w>>1)*32;
  f32x4 acc[4][2][2] = {};   // [gate][rowfrag][colfrag]
  for (int k0=0; k0<KCAT; k0+=64){
    #pragma unroll
    for (int q=0;q<2;q++){                 // A: 512 granules
      int idx = q*256 + w*64 + lane;
      int row = idx>>3, kg = (idx&7) ^ (row&7);
      load_lds16(Acat + (size_t)(r0+row)*KCAT + k0 + (kg<<3),
                 (char*)As + (q*256 + w*64)*16);
    }
    #pragma unroll
    for (int q=0;q<8;q++){                 // B: 2048 granules (4 gates x 64 cols)
      int idx = q*256 + w*64 + lane;
      int row = idx>>3, kg = (idx&7) ^ (row&7);
      int gate = row>>6, colr = row&63;
      load_lds16(Bf + (size_t)(gate*256 + c0 + colr)*KCAT + k0 + (kg<<3),
                 (char*)Bs + (q*256 + w*64)*16);
    }
    __syncthreads();
    #pragma unroll
    for (int kk=0;kk<2;kk++){
      bf16x8 a[2], bb[4][2];
      #pragma unroll
      for (int i=0;i<2;i++) a[i] = lds_frag64(As, rbase + i*16, lane, kk);
      #pragma unroll
      for (int g=0;g<4;g++)
        #pragma unroll
        for (int j=0;j<2;j++) bb[g][j] = lds_frag64(Bs, g*64 + cbase + j*16, lane, kk);
      #pragma unroll
      for (int g=0;g<4;g++)
        #pragma unroll
        for (int i=0;i<2;i++)
          #pragma unroll
          for (int j=0;j<2;j++)
            acc[g][i][j] = __builtin_amdgcn_mfma_f32_16x16x32_bf16(a[i], bb[g][j], acc[g][i][j], 0,0,0);
    }
    __syncthreads();
  }
  int grb = r0 + rbase;
  #pragma unroll
  for (int i=0;i<2;i++){
    #pragma unroll
    for (int j=0;j<2;j++){
      int gc = c0 + cbase + j*16 + (lane&15);
      float br_ = bih[gc]     + bhh[gc];
      float bz_ = bih[256+gc] + bhh[256+gc];
      float bnx = bih[512+gc];
      float bnh = bhh[512+gc];
      #pragma unroll
      for (int r=0;r<4;r++){
        int gr = grb + i*16 + ((lane>>4)<<2) + r;
        if (gr >= NNODES) continue;
        float hold = (float)Acat[(size_t)gr*KCAT + 256 + gc];
        float rr = fsig_(acc[0][i][j][r] + br_);
        float zz = fsig_(acc[1][i][j][r] + bz_);
        float nn = ftanh_(acc[2][i][j][r] + bnx + rr*(acc[3][i][j][r] + bnh));
        AcatN[(size_t)gr*KCAT + 256 + gc] = (__bf16)((1.f-zz)*nn + zz*hold);
      }
    }
  }
  // zero as_/ad_ for the next timestep's fused-alpha atomics
  if ((bid&3)==0 && (w>>1)==0 && (lane&15)==0){
    #pragma unroll
    for (int i=0;i<2;i++)
      #pragma unroll
      for (int r=0;r<4;r++){
        int gr = grb + i*16 + ((lane>>4)<<2) + r;
        if (gr < NNODES){ as_[gr] = 0.f; ad_[gr] = 0.f; }
      }
  }
}

// ---------------- launch ----------------
extern "C" void kernel_launch(void* const* d_in, const int* in_sizes, int n_in,
                              void* d_out, int out_size, void* d_ws, size_t ws_size,
                              hipStream_t stream) {
  const float* x_clique = (const float*)d_in[0];
  const float* W_gat    = (const float*)d_in[1];
  const float* att_src  = (const float*)d_in[2];
  const float* att_dst  = (const float*)d_in[3];
  const float* gat_bias = (const float*)d_in[4];
  const float* W_ih     = (const float*)d_in[5];
  const float* W_hh     = (const float*)d_in[6];
  const float* b_ih     = (const float*)d_in[7];
  const float* b_hh     = (const float*)d_in[8];
  const float* lin_W    = (const float*)d_in[9];
  const float* lin_b    = (const float*)d_in[10];
  const int*   eidx     = (const int*)d_in[14];
  float* out = (float*)d_out;

  const int* src = eidx;
  const int* dst = eidx + NEDGES;

  const size_t ACAT = (size_t)NROWP*KCAT;
  __bf16* AcA  = (__bf16*)d_ws;
  __bf16* AcB  = AcA + ACAT;
  __bf16* xpb  = AcB + ACAT;                        // [NROWP][256]
  __bf16* Bf   = xpb + (size_t)NROWP*HDIM;          // [1024][512]
  __bf16* wgb  = Bf  + (size_t)1024*KCAT;           // [256][256]
  __bf16* lwb  = wgb + (size_t)HDIM*HDIM;           // [128][256]
  float* as_   = (float*)(lwb + (size_t)ODIM*HDIM);
  float* ad_   = as_ + NNODES;
  int* deg     = (int*)(ad_ + NNODES);
  int* fill    = deg + NNODES;
  int* rowptr  = fill + NNODES;
  int* ssrc    = rowptr + (NNODES+1);

  // setup: 1 memset (deg+fill adjacent) + fused setup kernel + scan + scatter
  hipMemsetAsync(deg, 0, 2*NNODES*sizeof(int), stream);
  setup1_kernel<<<NNODES*64/256, 256, 0, stream>>>(
      dst, deg, x_clique, AcA, W_ih, W_hh, W_gat, lin_W, Bf, wgb, lwb, as_);
  scan_kernel<<<1, 1024, 0, stream>>>(deg, rowptr);
  scatter_kernel<<<(NEDGES+255)/256, 256, 0, stream>>>(src, dst, rowptr, fill, ssrc);

  const int RB64 = NROWP/64;   // 314
  __bf16* Ac = AcA;
  __bf16* An = AcB;
  for (int t=0; t<TSTEPS; t++){
    mfma_gemm_sm<2,false,true><<<RB64*2, 256, 0, stream>>>(
        Ac + 256, KCAT, wgb, nullptr, xpb, nullptr, HDIM, NNODES,
        att_src, att_dst, as_, ad_);
    gat_aggregate_kernel<<<(NNODES+3)/4, 256, 0, stream>>>(xpb, as_, ad_, rowptr, ssrc, gat_bias, Ac);
    gru_mfma_kernel<<<RB64*4, 256, 0, stream>>>(Ac, An, Bf, b_ih, b_hh, as_, ad_);
    __bf16* tmp = Ac; Ac = An; An = tmp;
  }
  mfma_gemm_sm<1,true,false><<<RB64, 256, 0, stream>>>(
      Ac + 256, KCAT, lwb, lin_b, nullptr, out, ODIM, NNODES,
      nullptr, nullptr, nullptr, nullptr);
}